// Round 1
// baseline (290.161 us; speedup 1.0000x reference)
//
#include <hip/hip_runtime.h>

typedef __attribute__((ext_vector_type(8))) __bf16 bf16x8;
typedef __attribute__((ext_vector_type(8))) unsigned short u16x8;
typedef __attribute__((ext_vector_type(4))) unsigned short u16x4;
typedef __attribute__((ext_vector_type(4))) float f32x4;

#define N_LOCI   59412
#define T_DIM    500
#define T_PAD    512
#define N_ENC    200
#define KL       29696
#define KR       29716
#define J_PAD    59648   // 233 * 256
#define NT2      233
#define G1_S     32      // split-K chunks for gemm1
#define G1_STEPS 30      // k-steps (of 32) per chunk: 32*30=960 >= 929

__device__ __forceinline__ unsigned short f2bf(float f) {
    unsigned int u = __float_as_uint(f);
    return (unsigned short)((u + 0x7FFFu + ((u >> 16) & 1u)) >> 16);  // RNE
}
__device__ __forceinline__ float bf2f(unsigned short h) {
    return __uint_as_float(((unsigned int)h) << 16);
}
__device__ __forceinline__ f32x4 mfma16(u16x8 a, u16x8 b, f32x4 c) {
    return __builtin_amdgcn_mfma_f32_16x16x32_bf16(
        __builtin_bit_cast(bf16x8, a), __builtin_bit_cast(bf16x8, b), c, 0, 0, 0);
}

// ---------------------------------------------------------------------------
// K1: per-row (locus) mean/norm of X; write normalized-centered bf16 X_hat
//     padded to [59648][512] with zeros (rows >= 59412, cols >= 500).
// One wave per row (500 f32 = 125 float4; lanes hold chunk l and l+64).
// ---------------------------------------------------------------------------
__global__ __launch_bounds__(256) void k1_xnorm(const float* __restrict__ X,
                                                unsigned short* __restrict__ Xh) {
    const int row  = blockIdx.x * 4 + (threadIdx.x >> 6);
    const int lane = threadIdx.x & 63;
    unsigned short* out = Xh + (size_t)row * T_PAD;
    if (row >= N_LOCI) {
        u16x4 z = {0, 0, 0, 0};
        *(u16x4*)(out + lane * 4) = z;
        *(u16x4*)(out + (lane + 64) * 4) = z;
        return;
    }
    const float4* xr = (const float4*)(X + (size_t)row * T_DIM);
    float4 v1 = xr[lane];
    float4 v2 = make_float4(0.f, 0.f, 0.f, 0.f);
    const bool has2 = (lane + 64) < 125;
    if (has2) v2 = xr[lane + 64];
    float s = v1.x + v1.y + v1.z + v1.w + v2.x + v2.y + v2.z + v2.w;
    float q = v1.x * v1.x + v1.y * v1.y + v1.z * v1.z + v1.w * v1.w
            + v2.x * v2.x + v2.y * v2.y + v2.z * v2.z + v2.w * v2.w;
    #pragma unroll
    for (int off = 32; off; off >>= 1) {
        s += __shfl_xor(s, off);
        q += __shfl_xor(q, off);
    }
    const float mean = s * (1.0f / 500.0f);
    const float inv  = rsqrtf(q - 500.0f * mean * mean);  // 1 / ||x - mean||
    u16x4 w1, w2 = {0, 0, 0, 0};
    w1[0] = f2bf((v1.x - mean) * inv);
    w1[1] = f2bf((v1.y - mean) * inv);
    w1[2] = f2bf((v1.z - mean) * inv);
    w1[3] = f2bf((v1.w - mean) * inv);
    if (has2) {
        w2[0] = f2bf((v2.x - mean) * inv);
        w2[1] = f2bf((v2.y - mean) * inv);
        w2[2] = f2bf((v2.z - mean) * inv);
        w2[3] = f2bf((v2.w - mean) * inv);
    }
    *(u16x4*)(out + lane * 4) = w1;
    *(u16x4*)(out + (lane + 64) * 4) = w2;
}

// ---------------------------------------------------------------------------
// K2: references = W_c @ X_slice, bf16 MFMA with in-kernel hi/lo f32 split
//     (3-term compensated product). Block tile M=256 (all 200 rows), N=128,
//     split-K over 32 chunks. Partials -> P[(comp*32+s)][256][512] f32.
// ---------------------------------------------------------------------------
__global__ __launch_bounds__(512) void k2_gemm1(const float* __restrict__ X,
                                                const float* __restrict__ WL,
                                                const float* __restrict__ WR,
                                                float* __restrict__ P) {
    const int ntile  = blockIdx.x;   // 0..3  (N slices of 128 within 512)
    const int schunk = blockIdx.y;   // 0..31 (split-K)
    const int comp   = blockIdx.z;   // 0..1
    const int K      = comp ? KR : KL;
    const float* W   = comp ? WR : WL;
    const int xbase  = comp ? KL : 0;
    const int n0     = ntile * 128;

    __shared__ unsigned short Ahs[256 * 40];
    __shared__ unsigned short Als[256 * 40];
    __shared__ unsigned short Bhs[128 * 40];
    __shared__ unsigned short Bls[128 * 40];

    const int t    = threadIdx.x;
    const int lane = t & 63;
    const int wid  = t >> 6;
    const int wm   = wid >> 1;  // 0..3 (64 rows each)
    const int wn   = wid & 1;   // 0..1 (64 cols each)

    f32x4 acc[4][4];
    #pragma unroll
    for (int i = 0; i < 4; ++i)
        #pragma unroll
        for (int j = 0; j < 4; ++j) {
            f32x4 z = {0.f, 0.f, 0.f, 0.f};
            acc[i][j] = z;
        }

    const int nsteps = (K + 31) >> 5;           // 928 (L) / 929 (R)
    const int ks0 = schunk * G1_STEPS;
    const int ks1 = (ks0 + G1_STEPS < nsteps) ? (ks0 + G1_STEPS) : nsteps;

    const int am = t >> 1, ah = t & 1;          // A staging: row am, 16-k half ah
    const int bn = t & 31, bk = t >> 5;         // B staging: base col bn, k-row bk

    for (int ks = ks0; ks < ks1; ++ks) {
        const int k0 = ks << 5;
        // ---- stage A = W[256 x 32] -> hi/lo bf16, layout [m][k], stride 40 ----
        {
            float vals[16];
            const int kb = k0 + 16 * ah;
            if (am < N_ENC) {
                const float* wrow = W + (size_t)am * K;
                #pragma unroll
                for (int f = 0; f < 4; ++f) {
                    const int kk = kb + 4 * f;
                    if (kk + 3 < K) {
                        const float4 v = *(const float4*)(wrow + kk);
                        vals[4 * f + 0] = v.x; vals[4 * f + 1] = v.y;
                        vals[4 * f + 2] = v.z; vals[4 * f + 3] = v.w;
                    } else {
                        #pragma unroll
                        for (int j = 0; j < 4; ++j)
                            vals[4 * f + j] = (kk + j < K) ? wrow[kk + j] : 0.0f;
                    }
                }
            } else {
                #pragma unroll
                for (int i = 0; i < 16; ++i) vals[i] = 0.0f;
            }
            u16x8 h0, h1, l0, l1;
            #pragma unroll
            for (int i = 0; i < 8; ++i) {
                unsigned short hh = f2bf(vals[i]);
                h0[i] = hh;
                l0[i] = f2bf(vals[i] - bf2f(hh));
            }
            #pragma unroll
            for (int i = 0; i < 8; ++i) {
                unsigned short hh = f2bf(vals[8 + i]);
                h1[i] = hh;
                l1[i] = f2bf(vals[8 + i] - bf2f(hh));
            }
            const int ao = am * 40 + 16 * ah;
            *(u16x8*)&Ahs[ao]     = h0;
            *(u16x8*)&Ahs[ao + 8] = h1;
            *(u16x8*)&Als[ao]     = l0;
            *(u16x8*)&Als[ao + 8] = l1;
        }
        // ---- stage B = X[32 x 128] transposed -> [n][k], stride 40 ----
        #pragma unroll
        for (int p = 0; p < 2; ++p) {
            const int kk   = bk + 16 * p;       // 0..31
            const int krel = k0 + kk;
            const bool kv  = krel < K;
            const float* xrow = X + (size_t)(xbase + krel) * T_DIM;
            #pragma unroll
            for (int i = 0; i < 4; ++i) {
                const int nl = bn + 32 * i;     // 0..127
                const int gc = n0 + nl;
                const float x = (kv && gc < T_DIM) ? xrow[gc] : 0.0f;
                const unsigned short hh = f2bf(x);
                Bhs[nl * 40 + kk] = hh;
                Bls[nl * 40 + kk] = f2bf(x - bf2f(hh));
            }
        }
        __syncthreads();
        // ---- MFMA: 3-term split per fragment pair ----
        u16x8 aH[4], aL[4], bH[4], bL[4];
        #pragma unroll
        for (int mf = 0; mf < 4; ++mf) {
            const int off = (wm * 64 + mf * 16 + (lane & 15)) * 40 + (lane >> 4) * 8;
            aH[mf] = *(const u16x8*)&Ahs[off];
            aL[mf] = *(const u16x8*)&Als[off];
        }
        #pragma unroll
        for (int nf = 0; nf < 4; ++nf) {
            const int off = (wn * 64 + nf * 16 + (lane & 15)) * 40 + (lane >> 4) * 8;
            bH[nf] = *(const u16x8*)&Bhs[off];
            bL[nf] = *(const u16x8*)&Bls[off];
        }
        #pragma unroll
        for (int mf = 0; mf < 4; ++mf)
            #pragma unroll
            for (int nf = 0; nf < 4; ++nf) {
                acc[mf][nf] = mfma16(aH[mf], bH[nf], acc[mf][nf]);
                acc[mf][nf] = mfma16(aH[mf], bL[nf], acc[mf][nf]);
                acc[mf][nf] = mfma16(aL[mf], bH[nf], acc[mf][nf]);
            }
        __syncthreads();
    }

    // write partials (always, even zero-step chunks: K3 sums all 32 slices)
    float* Pb = P + (size_t)(comp * G1_S + schunk) * 256 * 512;
    #pragma unroll
    for (int mf = 0; mf < 4; ++mf)
        #pragma unroll
        for (int nf = 0; nf < 4; ++nf)
            #pragma unroll
            for (int r = 0; r < 4; ++r) {
                const int m = wm * 64 + mf * 16 + (lane >> 4) * 4 + r;
                const int n = n0 + wn * 64 + nf * 16 + (lane & 15);
                Pb[(size_t)m * 512 + n] = acc[mf][nf][r];
            }
}

// ---------------------------------------------------------------------------
// K3: sum split-K partials, center+normalize reference rows -> A_hat bf16
//     [512][512] (rows >= 400 and cols >= 500 zeroed).
// ---------------------------------------------------------------------------
__global__ __launch_bounds__(256) void k3_astats(const float* __restrict__ P,
                                                 unsigned short* __restrict__ Ah) {
    const int r = blockIdx.x;   // 0..511
    const int t = threadIdx.x;  // 0..255
    unsigned short* out = Ah + (size_t)r * T_PAD;
    if (r >= 2 * N_ENC) { out[t] = 0; out[t + 256] = 0; return; }
    const int comp = (r >= N_ENC) ? 1 : 0;
    const int m = r - comp * N_ENC;
    float a1 = 0.0f, a2 = 0.0f;
    for (int s2 = 0; s2 < G1_S; ++s2) {
        const float* Pb = P + ((size_t)(comp * G1_S + s2) * 256 + m) * 512;
        a1 += Pb[t];
        a2 += Pb[t + 256];
    }
    const bool v2ok = (t + 256) < T_DIM;
    const float b2 = v2ok ? a2 : 0.0f;
    float s = a1 + b2;
    float q = a1 * a1 + b2 * b2;
    #pragma unroll
    for (int off = 32; off; off >>= 1) {
        s += __shfl_xor(s, off);
        q += __shfl_xor(q, off);
    }
    __shared__ float ls[4], lq[4];
    if ((t & 63) == 0) { ls[t >> 6] = s; lq[t >> 6] = q; }
    __syncthreads();
    const float S = ls[0] + ls[1] + ls[2] + ls[3];
    const float Q = lq[0] + lq[1] + lq[2] + lq[3];
    const float mean = S * (1.0f / 500.0f);
    const float inv  = rsqrtf(Q - 500.0f * mean * mean);
    out[t] = f2bf((a1 - mean) * inv);
    out[t + 256] = v2ok ? f2bf((a2 - mean) * inv) : (unsigned short)0;
}

// ---------------------------------------------------------------------------
// K4: C[400 x 59412] = A_hat @ X_hat^T (both rows unit-normalized, bf16,
//     fp32 MFMA accumulate, K=512). Block tile 128x256, 8 waves x (4x4) frags.
// ---------------------------------------------------------------------------
__global__ __launch_bounds__(512) void k4_gemm2(const unsigned short* __restrict__ Ahat,
                                                const unsigned short* __restrict__ Xhat,
                                                float* __restrict__ C) {
    const int j0 = blockIdx.x * 256;
    const int m0 = blockIdx.y * 128;
    __shared__ unsigned short As[128 * 40];
    __shared__ unsigned short Bs[256 * 40];
    const int t = threadIdx.x, lane = t & 63, wid = t >> 6;
    const int wm = wid >> 2, wn = wid & 3;
    f32x4 acc[4][4];
    #pragma unroll
    for (int i = 0; i < 4; ++i)
        #pragma unroll
        for (int j = 0; j < 4; ++j) {
            f32x4 z = {0.f, 0.f, 0.f, 0.f};
            acc[i][j] = z;
        }
    const int sm = t >> 2, sq = t & 3;
    const int sj = t >> 1, sh = t & 1;
    const unsigned short* arow = Ahat + (size_t)(m0 + sm) * T_PAD + 8 * sq;
    const unsigned short* brow = Xhat + (size_t)(j0 + sj) * T_PAD + 8 * sh;

    for (int ks = 0; ks < 16; ++ks) {
        const int k0 = ks * 32;
        const u16x8 av  = *(const u16x8*)(arow + k0);
        const u16x8 bv0 = *(const u16x8*)(brow + k0);
        const u16x8 bv1 = *(const u16x8*)(brow + k0 + 16);
        __syncthreads();
        *(u16x8*)&As[sm * 40 + 8 * sq] = av;
        *(u16x8*)&Bs[sj * 40 + 8 * sh] = bv0;
        *(u16x8*)&Bs[sj * 40 + 16 + 8 * sh] = bv1;
        __syncthreads();
        u16x8 af[4], bg[4];
        #pragma unroll
        for (int mf = 0; mf < 4; ++mf)
            af[mf] = *(const u16x8*)&As[(wm * 64 + mf * 16 + (lane & 15)) * 40 + (lane >> 4) * 8];
        #pragma unroll
        for (int nf = 0; nf < 4; ++nf)
            bg[nf] = *(const u16x8*)&Bs[(wn * 64 + nf * 16 + (lane & 15)) * 40 + (lane >> 4) * 8];
        #pragma unroll
        for (int mf = 0; mf < 4; ++mf)
            #pragma unroll
            for (int nf = 0; nf < 4; ++nf)
                acc[mf][nf] = mfma16(af[mf], bg[nf], acc[mf][nf]);
    }

    #pragma unroll
    for (int mf = 0; mf < 4; ++mf) {
        const int row = m0 + wm * 64 + mf * 16 + (lane >> 4) * 4;
        #pragma unroll
        for (int nf = 0; nf < 4; ++nf) {
            const int col = j0 + wn * 64 + nf * 16 + (lane & 15);
            if (col < N_LOCI) {
                #pragma unroll
                for (int rr = 0; rr < 4; ++rr) {
                    if (row + rr < 2 * N_ENC)
                        C[(size_t)(row + rr) * N_LOCI + col] = acc[mf][nf][rr];
                }
            }
        }
    }
}

// ---------------------------------------------------------------------------
extern "C" void kernel_launch(void* const* d_in, const int* in_sizes, int n_in,
                              void* d_out, int out_size, void* d_ws, size_t ws_size,
                              hipStream_t stream) {
    const float* X  = (const float*)d_in[0];
    const float* WL = (const float*)d_in[1];
    const float* WR = (const float*)d_in[2];
    float* C = (float*)d_out;

    // workspace layout:
    //   X_hat bf16 [59648][512]              : 61,079,552 B
    //   P     f32  [64][256][512]            : 33,554,432 B
    //   A_hat bf16 [512][512]                :    524,288 B
    const size_t xh_bytes = (size_t)J_PAD * T_PAD * 2;
    const size_t p_bytes  = (size_t)2 * G1_S * 256 * 512 * 4;
    unsigned short* Xh = (unsigned short*)d_ws;
    float* P           = (float*)((char*)d_ws + xh_bytes);
    unsigned short* Ah = (unsigned short*)((char*)d_ws + xh_bytes + p_bytes);

    k1_xnorm<<<dim3(J_PAD / 4), dim3(256), 0, stream>>>(X, Xh);
    k2_gemm1<<<dim3(4, G1_S, 2), dim3(512), 0, stream>>>(X, WL, WR, P);
    k3_astats<<<dim3(512), dim3(256), 0, stream>>>(P, Ah);
    k4_gemm2<<<dim3(NT2, 4), dim3(512), 0, stream>>>(Ah, Xh, C);
}

// Round 2
// 261.770 us; speedup vs baseline: 1.1085x; 1.1085x over previous
//
#include <hip/hip_runtime.h>

typedef __attribute__((ext_vector_type(8))) __bf16 bf16x8;
typedef __attribute__((ext_vector_type(8))) unsigned short u16x8;
typedef __attribute__((ext_vector_type(4))) unsigned short u16x4;
typedef __attribute__((ext_vector_type(4))) float f32x4;

#define N_LOCI   59412
#define T_DIM    500
#define T_PAD    512
#define N_ENC    200
#define KL       29696
#define KR       29716
#define J_PAD    59648   // 233 * 256
#define NT2      233
#define G1_S     32      // split-K chunks per compartment for gemm1

__device__ __forceinline__ unsigned short f2bf(float f) {
    unsigned int u = __float_as_uint(f);
    return (unsigned short)((u + 0x7FFFu + ((u >> 16) & 1u)) >> 16);  // RNE
}
__device__ __forceinline__ f32x4 mfma16(u16x8 a, u16x8 b, f32x4 c) {
    return __builtin_amdgcn_mfma_f32_16x16x32_bf16(
        __builtin_bit_cast(bf16x8, a), __builtin_bit_cast(bf16x8, b), c, 0, 0, 0);
}

// ---------------------------------------------------------------------------
// K1: per-row (locus) mean/norm of X; write normalized-centered bf16 X_hat
//     padded to [59648][512] with zeros (rows >= 59412, cols >= 500).
// ---------------------------------------------------------------------------
__global__ __launch_bounds__(256) void k1_xnorm(const float* __restrict__ X,
                                                unsigned short* __restrict__ Xh) {
    const int row  = blockIdx.x * 4 + (threadIdx.x >> 6);
    const int lane = threadIdx.x & 63;
    unsigned short* out = Xh + (size_t)row * T_PAD;
    if (row >= N_LOCI) {
        u16x4 z = {0, 0, 0, 0};
        *(u16x4*)(out + lane * 4) = z;
        *(u16x4*)(out + (lane + 64) * 4) = z;
        return;
    }
    const float4* xr = (const float4*)(X + (size_t)row * T_DIM);
    float4 v1 = xr[lane];
    float4 v2 = make_float4(0.f, 0.f, 0.f, 0.f);
    const bool has2 = (lane + 64) < 125;
    if (has2) v2 = xr[lane + 64];
    float s = v1.x + v1.y + v1.z + v1.w + v2.x + v2.y + v2.z + v2.w;
    float q = v1.x * v1.x + v1.y * v1.y + v1.z * v1.z + v1.w * v1.w
            + v2.x * v2.x + v2.y * v2.y + v2.z * v2.z + v2.w * v2.w;
    #pragma unroll
    for (int off = 32; off; off >>= 1) {
        s += __shfl_xor(s, off);
        q += __shfl_xor(q, off);
    }
    const float mean = s * (1.0f / 500.0f);
    const float inv  = rsqrtf(q - 500.0f * mean * mean);
    u16x4 w1, w2 = {0, 0, 0, 0};
    w1[0] = f2bf((v1.x - mean) * inv);
    w1[1] = f2bf((v1.y - mean) * inv);
    w1[2] = f2bf((v1.z - mean) * inv);
    w1[3] = f2bf((v1.w - mean) * inv);
    if (has2) {
        w2[0] = f2bf((v2.x - mean) * inv);
        w2[1] = f2bf((v2.y - mean) * inv);
        w2[2] = f2bf((v2.z - mean) * inv);
        w2[3] = f2bf((v2.w - mean) * inv);
    }
    *(u16x4*)(out + lane * 4) = w1;
    *(u16x4*)(out + (lane + 64) * 4) = w2;
}

// ---------------------------------------------------------------------------
// K2: references = W_c @ X_slice, plain bf16 MFMA (single term).
//     Block tile M=128, N=128, 4 waves (2x2 of 64x64), 256 threads.
//     Grid (8 = ntile|mtile, 32 split-K chunks, 2 comps) = 512 blocks.
//     Partials -> P[(comp*32+s)][200][512] f32.
// ---------------------------------------------------------------------------
__global__ __launch_bounds__(256) void k2_gemm1(const float* __restrict__ X,
                                                const float* __restrict__ WL,
                                                const float* __restrict__ WR,
                                                float* __restrict__ P) {
    const int ntile  = blockIdx.x & 3;
    const int mtile  = blockIdx.x >> 2;
    const int schunk = blockIdx.y;   // 0..31 (split-K)
    const int comp   = blockIdx.z;   // 0..1
    const int K      = comp ? KR : KL;
    const float* W   = comp ? WR : WL;
    const int xbase  = comp ? KL : 0;
    const int n0     = ntile * 128;
    const int m0     = mtile * 128;

    __shared__ unsigned short As[128 * 40];
    __shared__ unsigned short Bs[128 * 40];

    const int t    = threadIdx.x;
    const int lane = t & 63;
    const int wid  = t >> 6;
    const int wm   = wid >> 1;  // 0..1 (64 rows each)
    const int wn   = wid & 1;   // 0..1 (64 cols each)

    f32x4 acc[4][4];
    #pragma unroll
    for (int i = 0; i < 4; ++i)
        #pragma unroll
        for (int j = 0; j < 4; ++j) {
            f32x4 z = {0.f, 0.f, 0.f, 0.f};
            acc[i][j] = z;
        }

    const int nsteps = (K + 31) >> 5;               // 928 (L) / 929 (R)
    const int spc = (nsteps + G1_S - 1) / G1_S;     // 29 (L) / 30 (R)
    const int ks0 = schunk * spc;
    const int ks1 = (ks0 + spc < nsteps) ? (ks0 + spc) : nsteps;

    const int am = t >> 1, aseg = t & 1;   // A staging: row am (0..127), 16-k seg
    const int bn = t & 31, bk = t >> 5;    // B staging: base col bn, k-row bk (0..7)
    const int arow_g = m0 + am;
    const float* wrow = W + (size_t)arow_g * K;

    for (int ks = ks0; ks < ks1; ++ks) {
        const int k0 = ks << 5;
        // ---- stage A = W[128 x 32] -> bf16, layout [m][k], stride 40 ----
        {
            float vals[16];
            const int kb = k0 + 16 * aseg;
            if (arow_g < N_ENC) {
                if (kb + 15 < K) {
                    #pragma unroll
                    for (int f = 0; f < 4; ++f) {
                        const float4 v = *(const float4*)(wrow + kb + 4 * f);
                        vals[4 * f + 0] = v.x; vals[4 * f + 1] = v.y;
                        vals[4 * f + 2] = v.z; vals[4 * f + 3] = v.w;
                    }
                } else {
                    #pragma unroll
                    for (int j = 0; j < 16; ++j)
                        vals[j] = (kb + j < K) ? wrow[kb + j] : 0.0f;
                }
            } else {
                #pragma unroll
                for (int i = 0; i < 16; ++i) vals[i] = 0.0f;
            }
            u16x8 h0, h1;
            #pragma unroll
            for (int i = 0; i < 8; ++i) h0[i] = f2bf(vals[i]);
            #pragma unroll
            for (int i = 0; i < 8; ++i) h1[i] = f2bf(vals[8 + i]);
            const int ao = am * 40 + 16 * aseg;
            *(u16x8*)&As[ao]     = h0;
            *(u16x8*)&As[ao + 8] = h1;
        }
        // ---- stage B = X[32 x 128] transposed -> [n][k], stride 40 ----
        #pragma unroll
        for (int p = 0; p < 4; ++p) {
            const int kk   = bk + 8 * p;            // 0..31
            const int krel = k0 + kk;
            const bool kv  = krel < K;
            const float* xrow = X + (size_t)(xbase + krel) * T_DIM;
            #pragma unroll
            for (int i = 0; i < 4; ++i) {
                const int nl = bn + 32 * i;         // 0..127
                const int gc = n0 + nl;
                const float x = (kv && gc < T_DIM) ? xrow[gc] : 0.0f;
                Bs[nl * 40 + kk] = f2bf(x);
            }
        }
        __syncthreads();
        // ---- MFMA ----
        u16x8 af[4], bg[4];
        #pragma unroll
        for (int mf = 0; mf < 4; ++mf)
            af[mf] = *(const u16x8*)&As[(wm * 64 + mf * 16 + (lane & 15)) * 40 + (lane >> 4) * 8];
        #pragma unroll
        for (int nf = 0; nf < 4; ++nf)
            bg[nf] = *(const u16x8*)&Bs[(wn * 64 + nf * 16 + (lane & 15)) * 40 + (lane >> 4) * 8];
        #pragma unroll
        for (int mf = 0; mf < 4; ++mf)
            #pragma unroll
            for (int nf = 0; nf < 4; ++nf)
                acc[mf][nf] = mfma16(af[mf], bg[nf], acc[mf][nf]);
        __syncthreads();
    }

    // write partials (always, even zero-step chunks: K3 sums all 32 slices)
    float* Pb = P + (size_t)(comp * G1_S + schunk) * (200 * 512);
    #pragma unroll
    for (int mf = 0; mf < 4; ++mf)
        #pragma unroll
        for (int nf = 0; nf < 4; ++nf)
            #pragma unroll
            for (int r = 0; r < 4; ++r) {
                const int m = m0 + wm * 64 + mf * 16 + (lane >> 4) * 4 + r;
                const int n = n0 + wn * 64 + nf * 16 + (lane & 15);
                if (m < N_ENC)
                    Pb[(size_t)m * 512 + n] = acc[mf][nf][r];
            }
}

// ---------------------------------------------------------------------------
// K3: sum split-K partials, center+normalize reference rows -> A_hat bf16
//     [512][512] (rows >= 400 and cols >= 500 zeroed).
// ---------------------------------------------------------------------------
__global__ __launch_bounds__(256) void k3_astats(const float* __restrict__ P,
                                                 unsigned short* __restrict__ Ah) {
    const int r = blockIdx.x;   // 0..511
    const int t = threadIdx.x;  // 0..255
    unsigned short* out = Ah + (size_t)r * T_PAD;
    if (r >= 2 * N_ENC) { out[t] = 0; out[t + 256] = 0; return; }
    const int comp = (r >= N_ENC) ? 1 : 0;
    const int m = r - comp * N_ENC;
    float a1 = 0.0f, a2 = 0.0f;
    for (int s2 = 0; s2 < G1_S; ++s2) {
        const float* Pb = P + ((size_t)(comp * G1_S + s2) * 200 + m) * 512;
        a1 += Pb[t];
        a2 += Pb[t + 256];
    }
    const bool v2ok = (t + 256) < T_DIM;
    const float b2 = v2ok ? a2 : 0.0f;
    float s = a1 + b2;
    float q = a1 * a1 + b2 * b2;
    #pragma unroll
    for (int off = 32; off; off >>= 1) {
        s += __shfl_xor(s, off);
        q += __shfl_xor(q, off);
    }
    __shared__ float ls[4], lq[4];
    if ((t & 63) == 0) { ls[t >> 6] = s; lq[t >> 6] = q; }
    __syncthreads();
    const float S = ls[0] + ls[1] + ls[2] + ls[3];
    const float Q = lq[0] + lq[1] + lq[2] + lq[3];
    const float mean = S * (1.0f / 500.0f);
    const float inv  = rsqrtf(Q - 500.0f * mean * mean);
    out[t] = f2bf((a1 - mean) * inv);
    out[t + 256] = v2ok ? f2bf((a2 - mean) * inv) : (unsigned short)0;
}

// ---------------------------------------------------------------------------
// K4: C[400 x 59412] = A_hat @ X_hat^T (both rows unit-normalized, bf16,
//     fp32 MFMA accumulate, K=512). Block tile 128x256, 8 waves x (4x4) frags.
// ---------------------------------------------------------------------------
__global__ __launch_bounds__(512) void k4_gemm2(const unsigned short* __restrict__ Ahat,
                                                const unsigned short* __restrict__ Xhat,
                                                float* __restrict__ C) {
    const int j0 = blockIdx.x * 256;
    const int m0 = blockIdx.y * 128;
    __shared__ unsigned short As[128 * 40];
    __shared__ unsigned short Bs[256 * 40];
    const int t = threadIdx.x, lane = t & 63, wid = t >> 6;
    const int wm = wid >> 2, wn = wid & 3;
    f32x4 acc[4][4];
    #pragma unroll
    for (int i = 0; i < 4; ++i)
        #pragma unroll
        for (int j = 0; j < 4; ++j) {
            f32x4 z = {0.f, 0.f, 0.f, 0.f};
            acc[i][j] = z;
        }
    const int sm = t >> 2, sq = t & 3;
    const int sj = t >> 1, sh = t & 1;
    const unsigned short* arow = Ahat + (size_t)(m0 + sm) * T_PAD + 8 * sq;
    const unsigned short* brow = Xhat + (size_t)(j0 + sj) * T_PAD + 8 * sh;

    for (int ks = 0; ks < 16; ++ks) {
        const int k0 = ks * 32;
        const u16x8 av  = *(const u16x8*)(arow + k0);
        const u16x8 bv0 = *(const u16x8*)(brow + k0);
        const u16x8 bv1 = *(const u16x8*)(brow + k0 + 16);
        __syncthreads();
        *(u16x8*)&As[sm * 40 + 8 * sq] = av;
        *(u16x8*)&Bs[sj * 40 + 8 * sh] = bv0;
        *(u16x8*)&Bs[sj * 40 + 16 + 8 * sh] = bv1;
        __syncthreads();
        u16x8 af[4], bg[4];
        #pragma unroll
        for (int mf = 0; mf < 4; ++mf)
            af[mf] = *(const u16x8*)&As[(wm * 64 + mf * 16 + (lane & 15)) * 40 + (lane >> 4) * 8];
        #pragma unroll
        for (int nf = 0; nf < 4; ++nf)
            bg[nf] = *(const u16x8*)&Bs[(wn * 64 + nf * 16 + (lane & 15)) * 40 + (lane >> 4) * 8];
        #pragma unroll
        for (int mf = 0; mf < 4; ++mf)
            #pragma unroll
            for (int nf = 0; nf < 4; ++nf)
                acc[mf][nf] = mfma16(af[mf], bg[nf], acc[mf][nf]);
    }

    #pragma unroll
    for (int mf = 0; mf < 4; ++mf) {
        const int row = m0 + wm * 64 + mf * 16 + (lane >> 4) * 4;
        #pragma unroll
        for (int nf = 0; nf < 4; ++nf) {
            const int col = j0 + wn * 64 + nf * 16 + (lane & 15);
            if (col < N_LOCI) {
                #pragma unroll
                for (int rr = 0; rr < 4; ++rr) {
                    if (row + rr < 2 * N_ENC)
                        C[(size_t)(row + rr) * N_LOCI + col] = acc[mf][nf][rr];
                }
            }
        }
    }
}

// ---------------------------------------------------------------------------
extern "C" void kernel_launch(void* const* d_in, const int* in_sizes, int n_in,
                              void* d_out, int out_size, void* d_ws, size_t ws_size,
                              hipStream_t stream) {
    const float* X  = (const float*)d_in[0];
    const float* WL = (const float*)d_in[1];
    const float* WR = (const float*)d_in[2];
    float* C = (float*)d_out;

    // workspace layout:
    //   X_hat bf16 [59648][512]              : 61,079,552 B
    //   P     f32  [64][200][512]            : 26,214,400 B
    //   A_hat bf16 [512][512]                :    524,288 B
    //   total                                : 87,818,240 B
    const size_t xh_bytes = (size_t)J_PAD * T_PAD * 2;
    const size_t p_bytes  = (size_t)2 * G1_S * 200 * 512 * 4;
    unsigned short* Xh = (unsigned short*)d_ws;
    float* P           = (float*)((char*)d_ws + xh_bytes);
    unsigned short* Ah = (unsigned short*)((char*)d_ws + xh_bytes + p_bytes);

    k1_xnorm<<<dim3(J_PAD / 4), dim3(256), 0, stream>>>(X, Xh);
    k2_gemm1<<<dim3(8, G1_S, 2), dim3(256), 0, stream>>>(X, WL, WR, P);
    k3_astats<<<dim3(512), dim3(256), 0, stream>>>(P, Ah);
    k4_gemm2<<<dim3(NT2, 4), dim3(512), 0, stream>>>(Ah, Xh, C);
}